// Round 8
// baseline (62.175 us; speedup 1.0000x reference)
//
#include <hip/hip_runtime.h>

#define C_CH 64
#define NX 432
#define NY 496
#define NYQ 124                    // NY/4
#define PLANEQ (NX * NYQ)          // float4s per (b,c) plane = 53568

// ---------- fast path: memset(-1) + index scatter + plane-writer ----------

// Scatter pillar index m into map[s, NX-1-x, y] (flip pre-applied so the
// writer reads the map linearly).
__global__ void scatter_idx_kernel(const int* __restrict__ bidx,
                                   const int* __restrict__ sidx,
                                   int* __restrict__ map, int M) {
    int m = blockIdx.x * blockDim.x + threadIdx.x;
    if (m >= M) return;
    int y = bidx[3 * m + 1];
    int x = bidx[3 * m + 2];
    int s = sidx[m];
    map[(size_t)s * (NX * NY) + (size_t)(NX - 1 - x) * NY + y] = m;
}

// One block per (b,c) output plane: 256 blocks = 1 per CU. Each block writes
// its 857 KB plane as a single monotone contiguous stream (32 streams/XCD,
// fill-like DRAM page locality). q is linear in the plane, so the map read
// map4[b*PLANEQ+q] is fully coalesced (L2-served, 3.4 MB/XCD) and the store
// address is plane_base+q — zero div/mod in the loop. Scattered feats gathers
// (fixed c per block, ~5.6% of lanes active) are L2/L3-served and hidden by
// 16 waves/block.
__global__ __launch_bounds__(1024) void plane_write_kernel(
        const float* __restrict__ feats,
        const int4* __restrict__ map4,
        float4* __restrict__ out) {
    const int plane = blockIdx.x;           // b*C_CH + c
    const int b = plane >> 6;
    const int c = plane & (C_CH - 1);

    const int4* mp = map4 + (size_t)b * PLANEQ;
    float4* ob = out + (size_t)plane * PLANEQ;

    for (int q = threadIdx.x; q < PLANEQ; q += 1024) {
        int4 mm = mp[q];
        float4 v = make_float4(0.f, 0.f, 0.f, 0.f);
        if (mm.x >= 0) v.x = feats[(size_t)mm.x * C_CH + c];
        if (mm.y >= 0) v.y = feats[(size_t)mm.y * C_CH + c];
        if (mm.z >= 0) v.z = feats[(size_t)mm.z * C_CH + c];
        if (mm.w >= 0) v.w = feats[(size_t)mm.w * C_CH + c];
        ob[q] = v;
    }
}

// ---------- fallback path (if d_ws too small): zero + direct scatter ----------

__global__ void zero_out_kernel(float4* __restrict__ out, int nq) {
    int i = blockIdx.x * blockDim.x + threadIdx.x;
    if (i < nq) out[i] = make_float4(0.f, 0.f, 0.f, 0.f);
}

__global__ void scatter_feats_kernel(const float* __restrict__ feats,
                                     const int* __restrict__ bidx,
                                     const int* __restrict__ sidx,
                                     float* __restrict__ out, int M) {
    int tid = blockIdx.x * blockDim.x + threadIdx.x;
    if (tid >= M * C_CH) return;
    int m = tid >> 6;
    int c = tid & (C_CH - 1);
    int y = bidx[3 * m + 1];
    int x = bidx[3 * m + 2];
    int s = sidx[m];
    size_t o = (((size_t)s * C_CH + c) * NX + (NX - 1 - x)) * NY + y;
    out[o] = feats[tid];
}

extern "C" void kernel_launch(void* const* d_in, const int* in_sizes, int n_in,
                              void* d_out, int out_size, void* d_ws, size_t ws_size,
                              hipStream_t stream) {
    const float* feats = (const float*)d_in[0];
    const int*   bidx  = (const int*)d_in[1];
    const int*   sidx  = (const int*)d_in[2];
    float*       out   = (float*)d_out;

    const int M = in_sizes[0] / C_CH;               // 48000 pillars total
    const int B = out_size / (C_CH * NX * NY);      // 4

    const size_t map_elems = (size_t)B * NX * NY;   // 857,088
    const size_t map_bytes = map_elems * sizeof(int);

    if (ws_size >= map_bytes) {
        int* map = (int*)d_ws;
        // 0xFFFFFFFF == -1 as int32; DMA fill.
        hipMemsetAsync(map, 0xFF, map_bytes, stream);
        scatter_idx_kernel<<<(M + 255) / 256, 256, 0, stream>>>(bidx, sidx, map, M);
        plane_write_kernel<<<B * C_CH, 1024, 0, stream>>>(
            feats, (const int4*)map, (float4*)out);
    } else {
        int nq = out_size / 4;
        zero_out_kernel<<<(nq + 255) / 256, 256, 0, stream>>>((float4*)out, nq);
        int nt = M * C_CH;
        scatter_feats_kernel<<<(nt + 255) / 256, 256, 0, stream>>>(
            feats, bidx, sidx, out, M);
    }
}

// Round 9
// 49.667 us; speedup vs baseline: 1.2518x; 1.2518x over previous
//
#include <hip/hip_runtime.h>

#define C_CH 64
#define NX 432
#define NY 496
#define NYQ 124                    // NY/4
#define PLANEQ (NX * NYQ)          // float4s per (b,c) plane = 53568
#define SLOTS 96                   // staged pillars/column (expected ~28, Poisson tail << 1e-12)

// ---------- fast path: memset(-1) + index scatter + LDS-staged column writer ----------

// Scatter pillar index m into map[s, NX-1-x, y] (flip pre-applied so the
// writer reads its column slice contiguously).
__global__ void scatter_idx_kernel(const int* __restrict__ bidx,
                                   const int* __restrict__ sidx,
                                   int* __restrict__ map, int M) {
    int m = blockIdx.x * blockDim.x + threadIdx.x;
    if (m >= M) return;
    int y = bidx[3 * m + 1];
    int x = bidx[3 * m + 2];
    int s = sidx[m];
    map[(size_t)s * (NX * NY) + (size_t)(NX - 1 - x) * NY + y] = m;
}

// One block per (b, xo) column. Stores are fed ONLY from LDS — no global-load
// dependency in the store loop, so the 219 MB write stream issues at wire
// speed while phases A/B (tiny, coalesced) provide the data.
__global__ __launch_bounds__(256) void column_write_kernel(
        const float* __restrict__ feats,
        const int* __restrict__ map,
        float4* __restrict__ out) {
    __shared__ int4  map4[NYQ];             // slot (>=0), -1 empty, <=-2 direct
    __shared__ int   slot_m[SLOTS];
    __shared__ float rows[SLOTS][C_CH + 1]; // +1 pad: bank = (s + c) % 32
    __shared__ int   cnt;

    int* map_row = (int*)map4;
    const int blk = blockIdx.x;
    const int b   = blk / NX;
    const int xo  = blk - b * NX;
    const int tid = threadIdx.x;

    if (tid == 0) cnt = 0;
    __syncthreads();

    // Phase A: read column map slice (contiguous 496 ints), compact into slots
    const int* mp = map + ((size_t)b * NX + xo) * NY;
    for (int y = tid; y < NY; y += 256) {
        int m = mp[y];
        int v = -1;
        if (m >= 0) {
            int s = atomicAdd(&cnt, 1);
            if (s < SLOTS) { slot_m[s] = m; v = s; }
            else v = -2 - m;                // overflow: direct gather in phase C
        }
        map_row[y] = v;
    }
    __syncthreads();

    // Phase B: coalesced fetch of occupied pillar rows (256 B each) into LDS
    const int n = (cnt < SLOTS) ? cnt : SLOTS;
    for (int e = tid; e < n * C_CH; e += 256) {
        int s = e >> 6;
        int c = e & (C_CH - 1);
        rows[s][c] = feats[(size_t)slot_m[s] * C_CH + c];
    }
    __syncthreads();

    // Phase C: stream the (C=64, NYQ=124) slice. 128-thread group per c-plane
    // row -> 124 consecutive float4 stores (1984 B contiguous). Map quad is
    // loop-invariant per thread (hoisted). All loads are LDS.
    const int t    = tid & 127;             // yq
    const int cof  = tid >> 7;              // 0/1
    int4 mm = make_int4(-1, -1, -1, -1);
    if (t < NYQ) mm = map4[t];
    float4* ob = out + ((size_t)b * C_CH * NX + xo) * NYQ + t;

    #pragma unroll 4
    for (int c2 = 0; c2 < C_CH / 2; ++c2) {
        int c = (c2 << 1) + cof;
        if (t < NYQ) {
            float4 v = make_float4(0.f, 0.f, 0.f, 0.f);
            if (mm.x >= 0) v.x = rows[mm.x][c];
            else if (mm.x < -1) v.x = feats[(size_t)(-2 - mm.x) * C_CH + c];
            if (mm.y >= 0) v.y = rows[mm.y][c];
            else if (mm.y < -1) v.y = feats[(size_t)(-2 - mm.y) * C_CH + c];
            if (mm.z >= 0) v.z = rows[mm.z][c];
            else if (mm.z < -1) v.z = feats[(size_t)(-2 - mm.z) * C_CH + c];
            if (mm.w >= 0) v.w = rows[mm.w][c];
            else if (mm.w < -1) v.w = feats[(size_t)(-2 - mm.w) * C_CH + c];
            ob[(size_t)c * PLANEQ] = v;
        }
    }
}

// ---------- fallback path (if d_ws too small): zero + direct scatter ----------

__global__ void zero_out_kernel(float4* __restrict__ out, int nq) {
    int i = blockIdx.x * blockDim.x + threadIdx.x;
    if (i < nq) out[i] = make_float4(0.f, 0.f, 0.f, 0.f);
}

__global__ void scatter_feats_kernel(const float* __restrict__ feats,
                                     const int* __restrict__ bidx,
                                     const int* __restrict__ sidx,
                                     float* __restrict__ out, int M) {
    int tid = blockIdx.x * blockDim.x + threadIdx.x;
    if (tid >= M * C_CH) return;
    int m = tid >> 6;
    int c = tid & (C_CH - 1);
    int y = bidx[3 * m + 1];
    int x = bidx[3 * m + 2];
    int s = sidx[m];
    size_t o = (((size_t)s * C_CH + c) * NX + (NX - 1 - x)) * NY + y;
    out[o] = feats[tid];
}

extern "C" void kernel_launch(void* const* d_in, const int* in_sizes, int n_in,
                              void* d_out, int out_size, void* d_ws, size_t ws_size,
                              hipStream_t stream) {
    const float* feats = (const float*)d_in[0];
    const int*   bidx  = (const int*)d_in[1];
    const int*   sidx  = (const int*)d_in[2];
    float*       out   = (float*)d_out;

    const int M = in_sizes[0] / C_CH;               // 48000 pillars total
    const int B = out_size / (C_CH * NX * NY);      // 4

    const size_t map_elems = (size_t)B * NX * NY;   // 857,088
    const size_t map_bytes = map_elems * sizeof(int);

    if (ws_size >= map_bytes) {
        int* map = (int*)d_ws;
        hipMemsetAsync(map, 0xFF, map_bytes, stream);   // -1 fill
        scatter_idx_kernel<<<(M + 255) / 256, 256, 0, stream>>>(bidx, sidx, map, M);
        column_write_kernel<<<B * NX, 256, 0, stream>>>(
            feats, map, (float4*)out);
    } else {
        int nq = out_size / 4;
        zero_out_kernel<<<(nq + 255) / 256, 256, 0, stream>>>((float4*)out, nq);
        int nt = M * C_CH;
        scatter_feats_kernel<<<(nt + 255) / 256, 256, 0, stream>>>(
            feats, bidx, sidx, out, M);
    }
}